// Round 15
// baseline (229.364 us; speedup 1.0000x reference)
//
#include <hip/hip_runtime.h>
#include <math.h>

#define NB 32
#define NT 2048
#define NC 1024
#define NH 8
#define ND 128
#define TCH 32                       // t-chunks per batch; chunk = 64 rows
#define SCALE_F 0.08838834764831845f // 1/sqrt(128)

// DPP full-wave sum: VALU-pipe only (no ds_bpermute), ~24-cyc chain.
template <int CTRL>
__device__ __forceinline__ float dppadd(float x) {
  int t = __builtin_amdgcn_update_dpp(0, __float_as_int(x), CTRL, 0xf, 0xf, true);
  return x + __int_as_float(t);
}
__device__ __forceinline__ float wredsum(float v) {
  v = dppadd<0x111>(v);  // row_shr:1
  v = dppadd<0x112>(v);  // row_shr:2
  v = dppadd<0x114>(v);  // row_shr:4
  v = dppadd<0x118>(v);  // row_shr:8  -> lanes 15/31/47/63 hold row sums
  v = dppadd<0x142>(v);  // row_bcast:15
  v = dppadd<0x143>(v);  // row_bcast:31 -> lane63 = total
  return __int_as_float(__builtin_amdgcn_readlane(__float_as_int(v), 63));
}

// raw barrier: lgkm-only wait (ds_writes visible), NO vmcnt drain.
__device__ __forceinline__ void barx() {
  asm volatile("s_waitcnt lgkmcnt(0)" ::: "memory");
  __builtin_amdgcn_s_barrier();
  asm volatile("" ::: "memory");
}

// Fused q + split-K wq partial; 128 blocks = 8h x 16dq (8 d-rows each).
__global__ __launch_bounds__(256) void k_wqp(const float* __restrict__ qt,
                                             const float* __restrict__ q_w,
                                             const float* __restrict__ q_b,
                                             const float* __restrict__ kv_w,
                                             float* __restrict__ qout,
                                             float* __restrict__ wqp) {
  __shared__ float qs[8];
  int h = blockIdx.x >> 4, dq = blockIdx.x & 15;
  int tid = threadIdx.x;
  int dbase = h * ND + dq * 8;
  {
    int row = tid >> 5;  // 8 rows x 32 threads
    int cg = tid & 31;
    const float4* qw4 = (const float4*)(q_w + (size_t)(dbase + row) * NC);
    const float4* qt4 = (const float4*)qt;
    float p = 0.f;
#pragma unroll 8
    for (int j = 0; j < 8; ++j) {
      float4 wv = qw4[j * 32 + cg];
      float4 av = qt4[j * 32 + cg];
      p += av.x * wv.x + av.y * wv.y + av.z * wv.z + av.w * wv.w;
    }
    p += __shfl_xor(p, 1, 64);
    p += __shfl_xor(p, 2, 64);
    p += __shfl_xor(p, 4, 64);
    p += __shfl_xor(p, 8, 64);
    p += __shfl_xor(p, 16, 64);
    if (cg == 0) qs[row] = p + q_b[dbase + row];
  }
  __syncthreads();
  if (tid < 8) qout[dbase + tid] = qs[tid];
  const float4* kw4 = (const float4*)kv_w;
  float4 acc = make_float4(0.f, 0.f, 0.f, 0.f);
#pragma unroll 8
  for (int dd = 0; dd < 8; ++dd) {
    float qv = qs[dd];
    float4 kv = kw4[(size_t)(dbase + dd) * 256 + tid];
    acc.x = fmaf(qv, kv.x, acc.x); acc.y = fmaf(qv, kv.y, acc.y);
    acc.z = fmaf(qv, kv.z, acc.z); acc.w = fmaf(qv, kv.w, acc.w);
  }
  ((float4*)wqp)[dq * 2048 + h * 256 + tid] = acc;
}

// Single pass over x. TCH=32: grid 1024 = 4 blocks/CU for barrier overlap.
// R9-validated TCH-32 plumbing + DPP wredsum (R14-validated).
__global__ __launch_bounds__(256, 2) void k_fused(
    const float* __restrict__ x, const int* __restrict__ mask,
    const float* __restrict__ wqp, const float* __restrict__ q,
    const float* __restrict__ kv_b,
    float* __restrict__ S, float* __restrict__ partAcc,
    float* __restrict__ partML) {
  __shared__ float4 xs4[2 * 512];  // 2 slots x 2 rows x 256 float4 = 16 KB
  int bi = blockIdx.x;  // b*TCH + tc
  int b = bi >> 5;
  int tc = bi & (TCH - 1);
  int tid = threadIdx.x;
  int w = tid >> 6, lane = tid & 63;
  int h0 = w * 2;
  int tbase = tc * 64;

  const float4* wqp4 = (const float4*)wqp;
  float4 wqv[2][4];
#pragma unroll
  for (int hh = 0; hh < 2; ++hh)
#pragma unroll
    for (int j = 0; j < 4; ++j) {
      int idx = (h0 + hh) * 256 + lane + 64 * j;
      float sx = 0.f, sy = 0.f, sz = 0.f, sw = 0.f;
#pragma unroll
      for (int p = 0; p < 16; ++p) {
        float4 t = wqp4[p * 2048 + idx];
        sx += t.x; sy += t.y; sz += t.z; sw += t.w;
      }
      wqv[hh][j] = make_float4(sx, sy, sz, sw);
    }
  float qkbv[2];
#pragma unroll
  for (int hh = 0; hh < 2; ++hh) {
    float p = 0.f;
    if (lane < 32) {
      float4 qv = ((const float4*)(q + (h0 + hh) * ND))[lane];
      float4 bv = ((const float4*)(kv_b + (h0 + hh) * ND))[lane];
      p = qv.x * bv.x + qv.y * bv.y + qv.z * bv.z + qv.w * bv.w;
    }
    qkbv[hh] = wredsum(p);
  }
  unsigned long long bm = __ballot(mask[b * NT + tbase + lane] != 0);

  float m[2] = {-INFINITY, -INFINITY};
  float l[2] = {0.f, 0.f};
  float4 acc[2][4];
#pragma unroll
  for (int hh = 0; hh < 2; ++hh)
#pragma unroll
    for (int j = 0; j < 4; ++j) acc[hh][j] = make_float4(0.f, 0.f, 0.f, 0.f);
  float sreg[2][2] = {{0.f, 0.f}, {0.f, 0.f}};

  const float4* x4 = (const float4*)(x + (size_t)(b * NT + tbase) * NC);

  {
    float4 s0 = x4[tid], s1 = x4[256 + tid];
    xs4[tid] = s0;
    xs4[256 + tid] = s1;
  }
  barx();
  float4 pa0 = x4[2 * 256 + tid], pa1 = x4[3 * 256 + tid];
  float4 pb0 = x4[4 * 256 + tid], pb1 = x4[5 * 256 + tid];

#define COMPUTE_STEP(STEP, SLOT)                                               \
  {                                                                            \
    int t0 = tbase + (STEP) * 2;                                               \
    int mk0 = (int)((bm >> (unsigned)(2 * (STEP))) & 1ull);                    \
    int mk1 = (int)((bm >> (unsigned)(2 * (STEP) + 1)) & 1ull);                \
    float bias0 = 2.0f * __expf((float)t0 * (-3.0f / 2048.0f));                \
    float bias1 = 2.0f * __expf((float)(t0 + 1) * (-3.0f / 2048.0f));          \
    float4 xv[2][4];                                                           \
    _Pragma("unroll") for (int r = 0; r < 2; ++r)                              \
        _Pragma("unroll") for (int j = 0; j < 4; ++j)                          \
            xv[r][j] = xs4[(SLOT) * 512 + r * 256 + lane + 64 * j];            \
    _Pragma("unroll") for (int hh = 0; hh < 2; ++hh) {                         \
      float d0 = 0.f, d1 = 0.f;                                                \
      _Pragma("unroll") for (int j = 0; j < 4; ++j) {                          \
        float4 wv = wqv[hh][j];                                                \
        d0 = fmaf(xv[0][j].x, wv.x, d0); d0 = fmaf(xv[0][j].y, wv.y, d0);      \
        d0 = fmaf(xv[0][j].z, wv.z, d0); d0 = fmaf(xv[0][j].w, wv.w, d0);      \
        d1 = fmaf(xv[1][j].x, wv.x, d1); d1 = fmaf(xv[1][j].y, wv.y, d1);      \
        d1 = fmaf(xv[1][j].z, wv.z, d1); d1 = fmaf(xv[1][j].w, wv.w, d1);      \
      }                                                                        \
      d0 = wredsum(d0);                                                        \
      d1 = wredsum(d1);                                                        \
      float v0 = mk0 ? (d0 + qkbv[hh]) * SCALE_F + bias0 : -INFINITY;          \
      float v1 = mk1 ? (d1 + qkbv[hh]) * SCALE_F + bias1 : -INFINITY;          \
      sreg[hh][0] = (lane == (STEP)) ? v0 : sreg[hh][0];                       \
      sreg[hh][1] = (lane == (STEP)) ? v1 : sreg[hh][1];                       \
      float pmax = fmaxf(v0, v1);                                              \
      if (pmax > m[hh] + 8.0f) { /* defer-max; wave-uniform */                 \
        float r = __expf(m[hh] - pmax);                                        \
        l[hh] *= r;                                                            \
        _Pragma("unroll") for (int j = 0; j < 4; ++j) {                        \
          acc[hh][j].x *= r; acc[hh][j].y *= r;                                \
          acc[hh][j].z *= r; acc[hh][j].w *= r;                                \
        }                                                                      \
        m[hh] = pmax;                                                          \
      }                                                                        \
      float p0 = mk0 ? __expf(v0 - m[hh]) : 0.f;                               \
      float p1 = mk1 ? __expf(v1 - m[hh]) : 0.f;                               \
      l[hh] += p0 + p1;                                                        \
      _Pragma("unroll") for (int j = 0; j < 4; ++j) {                          \
        acc[hh][j].x = fmaf(p0, xv[0][j].x, fmaf(p1, xv[1][j].x, acc[hh][j].x)); \
        acc[hh][j].y = fmaf(p0, xv[0][j].y, fmaf(p1, xv[1][j].y, acc[hh][j].y)); \
        acc[hh][j].z = fmaf(p0, xv[0][j].z, fmaf(p1, xv[1][j].z, acc[hh][j].z)); \
        acc[hh][j].w = fmaf(p0, xv[0][j].w, fmaf(p1, xv[1][j].w, acc[hh][j].w)); \
      }                                                                        \
    }                                                                          \
  }

  for (int k = 0; k < 16; ++k) {
    COMPUTE_STEP(2 * k, 0)
    xs4[512 + tid] = pa0;
    xs4[512 + 256 + tid] = pa1;
    if (k < 15) {
      pa0 = x4[(4 * k + 6) * 256 + tid];
      pa1 = x4[(4 * k + 7) * 256 + tid];
    }
    barx();
    COMPUTE_STEP(2 * k + 1, 1)
    if (k < 15) {
      xs4[tid] = pb0;
      xs4[256 + tid] = pb1;
      if (k < 14) {
        pb0 = x4[(4 * k + 8) * 256 + tid];
        pb1 = x4[(4 * k + 9) * 256 + tid];
      }
      barx();
    }
  }
#undef COMPUTE_STEP

  // raw-score store: ONLY lanes 0..31 own rows (R4 lesson; 32 steps)
  if (lane < 32) {
#pragma unroll
    for (int hh = 0; hh < 2; ++hh) {
      float2 sv = make_float2(sreg[hh][0], sreg[hh][1]);
      float2* sp = (float2*)(S + ((size_t)(b * NH + h0 + hh)) * NT + tbase);
      sp[lane] = sv;
    }
  }
  float4* pA = (float4*)(partAcc + (size_t)bi * (NH * NC));
#pragma unroll
  for (int hh = 0; hh < 2; ++hh)
#pragma unroll
    for (int j = 0; j < 4; ++j)
      pA[(h0 + hh) * 256 + lane + 64 * j] = acc[hh][j];
  if (lane == 0) {
#pragma unroll
    for (int hh = 0; hh < 2; ++hh) {
      partML[(bi * NH + h0 + hh) * 2] = m[hh];
      partML[(bi * NH + h0 + hh) * 2 + 1] = l[hh];
    }
  }
}

// Merged xa-reduce + attn_weights (R9/R10-validated TCH-32 reductions).
__global__ __launch_bounds__(256) void k_xaw(const float* __restrict__ partAcc,
                                             const float* __restrict__ partML,
                                             const float* __restrict__ S,
                                             float* __restrict__ xa,
                                             float* __restrict__ ow) {
  __shared__ float Ms[NH], Is[NH];
  int blk = blockIdx.x;
  int tid = threadIdx.x;
  if (blk < NB * NH) {  // ---- xa role ----
    int b = blk >> 3, h = blk & 7;
    float mv = -INFINITY, lv = 0.f;
    if (tid < 32) {
      mv = partML[((b * TCH + tid) * NH + h) * 2];
      lv = partML[((b * TCH + tid) * NH + h) * 2 + 1];
    }
    float Mg = mv;
#pragma unroll
    for (int off = 16; off > 0; off >>= 1) Mg = fmaxf(Mg, __shfl_xor(Mg, off, 64));
    float contrib = (tid < 32 && mv != -INFINITY) ? __expf(mv - Mg) * lv : 0.f;
#pragma unroll
    for (int off = 16; off > 0; off >>= 1) contrib += __shfl_xor(contrib, off, 64);
    if (tid == 0) {
      Ms[0] = Mg;
      Is[0] = (contrib > 0.f) ? 1.f / contrib : 0.f;
    }
    __syncthreads();
    float Mgb = Ms[0], inv = Is[0];
    float4 sacc = make_float4(0.f, 0.f, 0.f, 0.f);
    for (int tc = 0; tc < TCH; ++tc) {
      int pi = (b * TCH + tc) * NH + h;
      float mw = partML[pi * 2];
      if (mw == -INFINITY) continue;
      float scl = __expf(mw - Mgb);
      float4 v = ((const float4*)partAcc)[(size_t)pi * 256 + tid];
      sacc.x = fmaf(scl, v.x, sacc.x); sacc.y = fmaf(scl, v.y, sacc.y);
      sacc.z = fmaf(scl, v.z, sacc.z); sacc.w = fmaf(scl, v.w, sacc.w);
    }
    sacc.x *= inv; sacc.y *= inv; sacc.z *= inv; sacc.w *= inv;
    ((float4*)xa)[(size_t)blk * 256 + tid] = sacc;
  } else {  // ---- attn_weights role ----
    int blkb = blk - NB * NH;
    int b = blkb >> 3, tch = blkb & 7;
    int hh = tid >> 5, tcc = tid & 31;  // 8 heads x 32 chunks
    float mv = partML[((b * TCH + tcc) * NH + hh) * 2];
    float lv = partML[((b * TCH + tcc) * NH + hh) * 2 + 1];
    float Mg = mv;
#pragma unroll
    for (int off = 16; off > 0; off >>= 1) Mg = fmaxf(Mg, __shfl_xor(Mg, off, 64));
    float contrib = (mv != -INFINITY) ? __expf(mv - Mg) * lv : 0.f;
#pragma unroll
    for (int off = 16; off > 0; off >>= 1) contrib += __shfl_xor(contrib, off, 64);
    if (tcc == 0) {
      Ms[hh] = Mg;
      Is[hh] = (contrib > 0.f) ? 1.f / contrib : 0.f;
    }
    __syncthreads();
    int t = tch * 256 + tid;
    float a = 0.f;
#pragma unroll
    for (int h = 0; h < NH; ++h) {
      float s = S[((size_t)(b * NH + h)) * NT + t];
      a += (s == -INFINITY) ? 0.f : __expf(s - Ms[h]) * Is[h];
    }
    ow[(size_t)b * NT + t] = a * 0.125f;
  }
}

// p2: wave per (bgroup of 4, hd) — weight row loaded ONCE for 4 b's.
__global__ __launch_bounds__(256) void k_pv(const float* __restrict__ xa,
                                            const float* __restrict__ kv_w,
                                            const float* __restrict__ kv_b,
                                            float* __restrict__ p2) {
  int gw = (blockIdx.x * 256 + threadIdx.x) >> 6;  // [0, 8192)
  int lane = threadIdx.x & 63;
  int hd = gw & (NC - 1);
  int bg = gw >> 10;  // [0,8): b = 4*bg .. 4*bg+3
  int h = hd >> 7;
  const float4* w4 = (const float4*)(kv_w + ((size_t)(NC + hd)) * NC);
  float4 wv[4];
#pragma unroll
  for (int j = 0; j < 4; ++j) wv[j] = w4[lane + 64 * j];
  float accv[4] = {0.f, 0.f, 0.f, 0.f};
#pragma unroll
  for (int i = 0; i < 4; ++i) {
    const float4* a4 =
        (const float4*)(xa + ((size_t)((bg * 4 + i) * NH + h)) * NC);
#pragma unroll
    for (int j = 0; j < 4; ++j) {
      float4 a = a4[lane + 64 * j];
      accv[i] += a.x * wv[j].x + a.y * wv[j].y + a.z * wv[j].z + a.w * wv[j].w;
    }
  }
#pragma unroll
  for (int i = 0; i < 4; ++i) accv[i] = wredsum(accv[i]);
  if (lane == 0) {
    float bias = kv_b[NC + hd];
#pragma unroll
    for (int i = 0; i < 4; ++i)
      p2[(size_t)(bg * 4 + i) * NC + hd] = accv[i] + bias;
  }
}

// out: wave per (bgroup of 4, i) — same 4-b restructure as k_pv.
__global__ __launch_bounds__(256) void k_proj(const float* __restrict__ p2,
                                              const float* __restrict__ proj_w,
                                              const float* __restrict__ proj_b,
                                              float* __restrict__ out) {
  int gw = (blockIdx.x * 256 + threadIdx.x) >> 6;  // [0, 8192)
  int lane = threadIdx.x & 63;
  int i = gw & (NC - 1);
  int bg = gw >> 10;
  const float4* w4 = (const float4*)(proj_w + (size_t)i * NC);
  float4 wv[4];
#pragma unroll
  for (int j = 0; j < 4; ++j) wv[j] = w4[lane + 64 * j];
  float accv[4] = {0.f, 0.f, 0.f, 0.f};
#pragma unroll
  for (int k = 0; k < 4; ++k) {
    const float4* a4 = (const float4*)(p2 + (size_t)(bg * 4 + k) * NC);
#pragma unroll
    for (int j = 0; j < 4; ++j) {
      float4 a = a4[lane + 64 * j];
      accv[k] += a.x * wv[j].x + a.y * wv[j].y + a.z * wv[j].z + a.w * wv[j].w;
    }
  }
#pragma unroll
  for (int k = 0; k < 4; ++k) accv[k] = wredsum(accv[k]);
  if (lane == 0) {
    float bias = proj_b[i];
#pragma unroll
    for (int k = 0; k < 4; ++k)
      out[(size_t)(bg * 4 + k) * NC + i] = accv[k] + bias;
  }
}

extern "C" void kernel_launch(void* const* d_in, const int* in_sizes, int n_in,
                              void* d_out, int out_size, void* d_ws, size_t ws_size,
                              hipStream_t stream) {
  const float* x = (const float*)d_in[0];
  const int* mask = (const int*)d_in[1];
  const float* qt = (const float*)d_in[2];
  const float* kv_w = (const float*)d_in[3];
  const float* kv_b = (const float*)d_in[4];
  const float* q_w = (const float*)d_in[5];
  const float* q_b = (const float*)d_in[6];
  const float* proj_w = (const float*)d_in[7];
  const float* proj_b = (const float*)d_in[8];
  float* out = (float*)d_out;

  float* ws = (float*)d_ws;
  float* q = ws;                    // 1024
  float* wqp = ws + 1024;           // 16*8192 = 131072
  float* S = ws + 132096;           // 524288
  float* partAcc = ws + 656384;     // NB*TCH*NH*NC = 8388608 (32 MiB)
  float* partML = ws + 9044992;     // 16384
  float* xa = ws + 9061376;         // 262144
  float* p2 = ws + 9323520;         // 32768

  k_wqp<<<128, 256, 0, stream>>>(qt, q_w, q_b, kv_w, q, wqp);
  k_fused<<<NB * TCH, 256, 0, stream>>>(x, mask, wqp, q, kv_b, S, partAcc, partML);
  k_xaw<<<512, 256, 0, stream>>>(partAcc, partML, S, xa, out + NB * NC);
  k_pv<<<2048, 256, 0, stream>>>(xa, kv_w, kv_b, p2);
  k_proj<<<2048, 256, 0, stream>>>(p2, proj_w, proj_b, out);
}

// Round 16
// 144.202 us; speedup vs baseline: 1.5906x; 1.5906x over previous
//
#include <hip/hip_runtime.h>
#include <math.h>

#define NB 32
#define NT 2048
#define NC 1024
#define NH 8
#define ND 128
#define TCH 32                       // t-chunks per batch; chunk = 64 rows
#define SCALE_F 0.08838834764831845f // 1/sqrt(128)

// DPP full-wave sum: VALU-pipe only (no ds_bpermute), ~24-cyc chain.
template <int CTRL>
__device__ __forceinline__ float dppadd(float x) {
  int t = __builtin_amdgcn_update_dpp(0, __float_as_int(x), CTRL, 0xf, 0xf, true);
  return x + __int_as_float(t);
}
__device__ __forceinline__ float wredsum(float v) {
  v = dppadd<0x111>(v);  // row_shr:1
  v = dppadd<0x112>(v);  // row_shr:2
  v = dppadd<0x114>(v);  // row_shr:4
  v = dppadd<0x118>(v);  // row_shr:8  -> lanes 15/31/47/63 hold row sums
  v = dppadd<0x142>(v);  // row_bcast:15
  v = dppadd<0x143>(v);  // row_bcast:31 -> lane63 = total
  return __int_as_float(__builtin_amdgcn_readlane(__float_as_int(v), 63));
}

// raw barrier: lgkm-only wait (ds_writes visible), NO vmcnt drain.
__device__ __forceinline__ void barx() {
  asm volatile("s_waitcnt lgkmcnt(0)" ::: "memory");
  __builtin_amdgcn_s_barrier();
  asm volatile("" ::: "memory");
}

// Fused q + split-K wq partial; 64 blocks = 8h x 8dq (16 d-rows each).
// (R14-validated; R15's 128-block/16-partial variant caused k_fused spills.)
__global__ __launch_bounds__(256) void k_wqp(const float* __restrict__ qt,
                                             const float* __restrict__ q_w,
                                             const float* __restrict__ q_b,
                                             const float* __restrict__ kv_w,
                                             float* __restrict__ qout,
                                             float* __restrict__ wqp) {
  __shared__ float qs[16];
  int h = blockIdx.x >> 3, dq = blockIdx.x & 7;
  int tid = threadIdx.x;
  int dbase = h * ND + dq * 16;
  {
    int row = tid >> 4;  // 16 rows x 16 threads
    int cg = tid & 15;
    const float4* qw4 = (const float4*)(q_w + (size_t)(dbase + row) * NC);
    const float4* qt4 = (const float4*)qt;
    float p = 0.f;
#pragma unroll 8
    for (int j = 0; j < 16; ++j) {
      float4 wv = qw4[j * 16 + cg];
      float4 av = qt4[j * 16 + cg];
      p += av.x * wv.x + av.y * wv.y + av.z * wv.z + av.w * wv.w;
    }
    p += __shfl_xor(p, 1, 64);
    p += __shfl_xor(p, 2, 64);
    p += __shfl_xor(p, 4, 64);
    p += __shfl_xor(p, 8, 64);
    if (cg == 0) qs[row] = p + q_b[dbase + row];
  }
  __syncthreads();
  if (tid < 16) qout[dbase + tid] = qs[tid];
  const float4* kw4 = (const float4*)kv_w;
  float4 acc = make_float4(0.f, 0.f, 0.f, 0.f);
#pragma unroll 8
  for (int dd = 0; dd < 16; ++dd) {
    float qv = qs[dd];
    float4 kv = kw4[(size_t)(dbase + dd) * 256 + tid];
    acc.x = fmaf(qv, kv.x, acc.x); acc.y = fmaf(qv, kv.y, acc.y);
    acc.z = fmaf(qv, kv.z, acc.z); acc.w = fmaf(qv, kv.w, acc.w);
  }
  ((float4*)wqp)[dq * 2048 + h * 256 + tid] = acc;
}

// Single pass over x. TCH=32 (grid 1024 = 4 blocks/CU for barrier overlap),
// DPP wredsum. Spill fix vs R15: 8 partials summed with unroll-1 (serial,
// ~4 live regs) -> register demand stays under the 128-VGPR tier.
__global__ __launch_bounds__(256, 2) void k_fused(
    const float* __restrict__ x, const int* __restrict__ mask,
    const float* __restrict__ wqp, const float* __restrict__ q,
    const float* __restrict__ kv_b,
    float* __restrict__ S, float* __restrict__ partAcc,
    float* __restrict__ partML) {
  __shared__ float4 xs4[2 * 512];  // 2 slots x 2 rows x 256 float4 = 16 KB
  int bi = blockIdx.x;  // b*TCH + tc
  int b = bi >> 5;
  int tc = bi & (TCH - 1);
  int tid = threadIdx.x;
  int w = tid >> 6, lane = tid & 63;
  int h0 = w * 2;
  int tbase = tc * 64;

  const float4* wqp4 = (const float4*)wqp;
  float4 wqv[2][4];
#pragma unroll
  for (int hh = 0; hh < 2; ++hh)
#pragma unroll
    for (int j = 0; j < 4; ++j) {
      int idx = (h0 + hh) * 256 + lane + 64 * j;
      float sx = 0.f, sy = 0.f, sz = 0.f, sw = 0.f;
#pragma unroll 1  // SERIAL: keep load-in-flight count low (R15 spill lesson)
      for (int p = 0; p < 8; ++p) {
        float4 t = wqp4[p * 2048 + idx];
        sx += t.x; sy += t.y; sz += t.z; sw += t.w;
      }
      wqv[hh][j] = make_float4(sx, sy, sz, sw);
    }
  float qkbv[2];
#pragma unroll
  for (int hh = 0; hh < 2; ++hh) {
    float p = 0.f;
    if (lane < 32) {
      float4 qv = ((const float4*)(q + (h0 + hh) * ND))[lane];
      float4 bv = ((const float4*)(kv_b + (h0 + hh) * ND))[lane];
      p = qv.x * bv.x + qv.y * bv.y + qv.z * bv.z + qv.w * bv.w;
    }
    qkbv[hh] = wredsum(p);
  }
  unsigned long long bm = __ballot(mask[b * NT + tbase + lane] != 0);

  float m[2] = {-INFINITY, -INFINITY};
  float l[2] = {0.f, 0.f};
  float4 acc[2][4];
#pragma unroll
  for (int hh = 0; hh < 2; ++hh)
#pragma unroll
    for (int j = 0; j < 4; ++j) acc[hh][j] = make_float4(0.f, 0.f, 0.f, 0.f);
  float sreg[2][2] = {{0.f, 0.f}, {0.f, 0.f}};

  const float4* x4 = (const float4*)(x + (size_t)(b * NT + tbase) * NC);

  {
    float4 s0 = x4[tid], s1 = x4[256 + tid];
    xs4[tid] = s0;
    xs4[256 + tid] = s1;
  }
  barx();
  float4 pa0 = x4[2 * 256 + tid], pa1 = x4[3 * 256 + tid];
  float4 pb0 = x4[4 * 256 + tid], pb1 = x4[5 * 256 + tid];

#define COMPUTE_STEP(STEP, SLOT)                                               \
  {                                                                            \
    int t0 = tbase + (STEP) * 2;                                               \
    int mk0 = (int)((bm >> (unsigned)(2 * (STEP))) & 1ull);                    \
    int mk1 = (int)((bm >> (unsigned)(2 * (STEP) + 1)) & 1ull);                \
    float bias0 = 2.0f * __expf((float)t0 * (-3.0f / 2048.0f));                \
    float bias1 = 2.0f * __expf((float)(t0 + 1) * (-3.0f / 2048.0f));          \
    float4 xv[2][4];                                                           \
    _Pragma("unroll") for (int r = 0; r < 2; ++r)                              \
        _Pragma("unroll") for (int j = 0; j < 4; ++j)                          \
            xv[r][j] = xs4[(SLOT) * 512 + r * 256 + lane + 64 * j];            \
    _Pragma("unroll") for (int hh = 0; hh < 2; ++hh) {                         \
      float d0 = 0.f, d1 = 0.f;                                                \
      _Pragma("unroll") for (int j = 0; j < 4; ++j) {                          \
        float4 wv = wqv[hh][j];                                                \
        d0 = fmaf(xv[0][j].x, wv.x, d0); d0 = fmaf(xv[0][j].y, wv.y, d0);      \
        d0 = fmaf(xv[0][j].z, wv.z, d0); d0 = fmaf(xv[0][j].w, wv.w, d0);      \
        d1 = fmaf(xv[1][j].x, wv.x, d1); d1 = fmaf(xv[1][j].y, wv.y, d1);      \
        d1 = fmaf(xv[1][j].z, wv.z, d1); d1 = fmaf(xv[1][j].w, wv.w, d1);      \
      }                                                                        \
      d0 = wredsum(d0);                                                        \
      d1 = wredsum(d1);                                                        \
      float v0 = mk0 ? (d0 + qkbv[hh]) * SCALE_F + bias0 : -INFINITY;          \
      float v1 = mk1 ? (d1 + qkbv[hh]) * SCALE_F + bias1 : -INFINITY;          \
      sreg[hh][0] = (lane == (STEP)) ? v0 : sreg[hh][0];                       \
      sreg[hh][1] = (lane == (STEP)) ? v1 : sreg[hh][1];                       \
      float pmax = fmaxf(v0, v1);                                              \
      if (pmax > m[hh] + 8.0f) { /* defer-max; wave-uniform */                 \
        float r = __expf(m[hh] - pmax);                                        \
        l[hh] *= r;                                                            \
        _Pragma("unroll") for (int j = 0; j < 4; ++j) {                        \
          acc[hh][j].x *= r; acc[hh][j].y *= r;                                \
          acc[hh][j].z *= r; acc[hh][j].w *= r;                                \
        }                                                                      \
        m[hh] = pmax;                                                          \
      }                                                                        \
      float p0 = mk0 ? __expf(v0 - m[hh]) : 0.f;                               \
      float p1 = mk1 ? __expf(v1 - m[hh]) : 0.f;                               \
      l[hh] += p0 + p1;                                                        \
      _Pragma("unroll") for (int j = 0; j < 4; ++j) {                          \
        acc[hh][j].x = fmaf(p0, xv[0][j].x, fmaf(p1, xv[1][j].x, acc[hh][j].x)); \
        acc[hh][j].y = fmaf(p0, xv[0][j].y, fmaf(p1, xv[1][j].y, acc[hh][j].y)); \
        acc[hh][j].z = fmaf(p0, xv[0][j].z, fmaf(p1, xv[1][j].z, acc[hh][j].z)); \
        acc[hh][j].w = fmaf(p0, xv[0][j].w, fmaf(p1, xv[1][j].w, acc[hh][j].w)); \
      }                                                                        \
    }                                                                          \
  }

  for (int k = 0; k < 16; ++k) {
    COMPUTE_STEP(2 * k, 0)
    xs4[512 + tid] = pa0;
    xs4[512 + 256 + tid] = pa1;
    if (k < 15) {
      pa0 = x4[(4 * k + 6) * 256 + tid];
      pa1 = x4[(4 * k + 7) * 256 + tid];
    }
    barx();
    COMPUTE_STEP(2 * k + 1, 1)
    if (k < 15) {
      xs4[tid] = pb0;
      xs4[256 + tid] = pb1;
      if (k < 14) {
        pb0 = x4[(4 * k + 8) * 256 + tid];
        pb1 = x4[(4 * k + 9) * 256 + tid];
      }
      barx();
    }
  }
#undef COMPUTE_STEP

  // raw-score store: ONLY lanes 0..31 own rows (R4 lesson; 32 steps)
  if (lane < 32) {
#pragma unroll
    for (int hh = 0; hh < 2; ++hh) {
      float2 sv = make_float2(sreg[hh][0], sreg[hh][1]);
      float2* sp = (float2*)(S + ((size_t)(b * NH + h0 + hh)) * NT + tbase);
      sp[lane] = sv;
    }
  }
  float4* pA = (float4*)(partAcc + (size_t)bi * (NH * NC));
#pragma unroll
  for (int hh = 0; hh < 2; ++hh)
#pragma unroll
    for (int j = 0; j < 4; ++j)
      pA[(h0 + hh) * 256 + lane + 64 * j] = acc[hh][j];
  if (lane == 0) {
#pragma unroll
    for (int hh = 0; hh < 2; ++hh) {
      partML[(bi * NH + h0 + hh) * 2] = m[hh];
      partML[(bi * NH + h0 + hh) * 2 + 1] = l[hh];
    }
  }
}

// Merged xa-reduce + attn_weights (TCH-32 reductions; R9/R10-validated).
__global__ __launch_bounds__(256) void k_xaw(const float* __restrict__ partAcc,
                                             const float* __restrict__ partML,
                                             const float* __restrict__ S,
                                             float* __restrict__ xa,
                                             float* __restrict__ ow) {
  __shared__ float Ms[NH], Is[NH];
  int blk = blockIdx.x;
  int tid = threadIdx.x;
  if (blk < NB * NH) {  // ---- xa role ----
    int b = blk >> 3, h = blk & 7;
    float mv = -INFINITY, lv = 0.f;
    if (tid < 32) {
      mv = partML[((b * TCH + tid) * NH + h) * 2];
      lv = partML[((b * TCH + tid) * NH + h) * 2 + 1];
    }
    float Mg = mv;
#pragma unroll
    for (int off = 16; off > 0; off >>= 1) Mg = fmaxf(Mg, __shfl_xor(Mg, off, 64));
    float contrib = (tid < 32 && mv != -INFINITY) ? __expf(mv - Mg) * lv : 0.f;
#pragma unroll
    for (int off = 16; off > 0; off >>= 1) contrib += __shfl_xor(contrib, off, 64);
    if (tid == 0) {
      Ms[0] = Mg;
      Is[0] = (contrib > 0.f) ? 1.f / contrib : 0.f;
    }
    __syncthreads();
    float Mgb = Ms[0], inv = Is[0];
    float4 sacc = make_float4(0.f, 0.f, 0.f, 0.f);
    for (int tc = 0; tc < TCH; ++tc) {
      int pi = (b * TCH + tc) * NH + h;
      float mw = partML[pi * 2];
      if (mw == -INFINITY) continue;
      float scl = __expf(mw - Mgb);
      float4 v = ((const float4*)partAcc)[(size_t)pi * 256 + tid];
      sacc.x = fmaf(scl, v.x, sacc.x); sacc.y = fmaf(scl, v.y, sacc.y);
      sacc.z = fmaf(scl, v.z, sacc.z); sacc.w = fmaf(scl, v.w, sacc.w);
    }
    sacc.x *= inv; sacc.y *= inv; sacc.z *= inv; sacc.w *= inv;
    ((float4*)xa)[(size_t)blk * 256 + tid] = sacc;
  } else {  // ---- attn_weights role ----
    int blkb = blk - NB * NH;
    int b = blkb >> 3, tch = blkb & 7;
    int hh = tid >> 5, tcc = tid & 31;  // 8 heads x 32 chunks
    float mv = partML[((b * TCH + tcc) * NH + hh) * 2];
    float lv = partML[((b * TCH + tcc) * NH + hh) * 2 + 1];
    float Mg = mv;
#pragma unroll
    for (int off = 16; off > 0; off >>= 1) Mg = fmaxf(Mg, __shfl_xor(Mg, off, 64));
    float contrib = (mv != -INFINITY) ? __expf(mv - Mg) * lv : 0.f;
#pragma unroll
    for (int off = 16; off > 0; off >>= 1) contrib += __shfl_xor(contrib, off, 64);
    if (tcc == 0) {
      Ms[hh] = Mg;
      Is[hh] = (contrib > 0.f) ? 1.f / contrib : 0.f;
    }
    __syncthreads();
    int t = tch * 256 + tid;
    float a = 0.f;
#pragma unroll
    for (int h = 0; h < NH; ++h) {
      float s = S[((size_t)(b * NH + h)) * NT + t];
      a += (s == -INFINITY) ? 0.f : __expf(s - Ms[h]) * Is[h];
    }
    ow[(size_t)b * NT + t] = a * 0.125f;
  }
}

// p2: wave per (bgroup of 4, hd) — weight row loaded ONCE for 4 b's.
__global__ __launch_bounds__(256) void k_pv(const float* __restrict__ xa,
                                            const float* __restrict__ kv_w,
                                            const float* __restrict__ kv_b,
                                            float* __restrict__ p2) {
  int gw = (blockIdx.x * 256 + threadIdx.x) >> 6;  // [0, 8192)
  int lane = threadIdx.x & 63;
  int hd = gw & (NC - 1);
  int bg = gw >> 10;  // [0,8): b = 4*bg .. 4*bg+3
  int h = hd >> 7;
  const float4* w4 = (const float4*)(kv_w + ((size_t)(NC + hd)) * NC);
  float4 wv[4];
#pragma unroll
  for (int j = 0; j < 4; ++j) wv[j] = w4[lane + 64 * j];
  float accv[4] = {0.f, 0.f, 0.f, 0.f};
#pragma unroll
  for (int i = 0; i < 4; ++i) {
    const float4* a4 =
        (const float4*)(xa + ((size_t)((bg * 4 + i) * NH + h)) * NC);
#pragma unroll
    for (int j = 0; j < 4; ++j) {
      float4 a = a4[lane + 64 * j];
      accv[i] += a.x * wv[j].x + a.y * wv[j].y + a.z * wv[j].z + a.w * wv[j].w;
    }
  }
#pragma unroll
  for (int i = 0; i < 4; ++i) accv[i] = wredsum(accv[i]);
  if (lane == 0) {
    float bias = kv_b[NC + hd];
#pragma unroll
    for (int i = 0; i < 4; ++i)
      p2[(size_t)(bg * 4 + i) * NC + hd] = accv[i] + bias;
  }
}

// out: wave per (bgroup of 4, i) — same 4-b restructure as k_pv.
__global__ __launch_bounds__(256) void k_proj(const float* __restrict__ p2,
                                              const float* __restrict__ proj_w,
                                              const float* __restrict__ proj_b,
                                              float* __restrict__ out) {
  int gw = (blockIdx.x * 256 + threadIdx.x) >> 6;  // [0, 8192)
  int lane = threadIdx.x & 63;
  int i = gw & (NC - 1);
  int bg = gw >> 10;
  const float4* w4 = (const float4*)(proj_w + (size_t)i * NC);
  float4 wv[4];
#pragma unroll
  for (int j = 0; j < 4; ++j) wv[j] = w4[lane + 64 * j];
  float accv[4] = {0.f, 0.f, 0.f, 0.f};
#pragma unroll
  for (int k = 0; k < 4; ++k) {
    const float4* a4 = (const float4*)(p2 + (size_t)(bg * 4 + k) * NC);
#pragma unroll
    for (int j = 0; j < 4; ++j) {
      float4 a = a4[lane + 64 * j];
      accv[k] += a.x * wv[j].x + a.y * wv[j].y + a.z * wv[j].z + a.w * wv[j].w;
    }
  }
#pragma unroll
  for (int k = 0; k < 4; ++k) accv[k] = wredsum(accv[k]);
  if (lane == 0) {
    float bias = proj_b[i];
#pragma unroll
    for (int k = 0; k < 4; ++k)
      out[(size_t)(bg * 4 + k) * NC + i] = accv[k] + bias;
  }
}

extern "C" void kernel_launch(void* const* d_in, const int* in_sizes, int n_in,
                              void* d_out, int out_size, void* d_ws, size_t ws_size,
                              hipStream_t stream) {
  const float* x = (const float*)d_in[0];
  const int* mask = (const int*)d_in[1];
  const float* qt = (const float*)d_in[2];
  const float* kv_w = (const float*)d_in[3];
  const float* kv_b = (const float*)d_in[4];
  const float* q_w = (const float*)d_in[5];
  const float* q_b = (const float*)d_in[6];
  const float* proj_w = (const float*)d_in[7];
  const float* proj_b = (const float*)d_in[8];
  float* out = (float*)d_out;

  float* ws = (float*)d_ws;
  float* q = ws;                    // 1024
  float* wqp = ws + 1024;           // 8*8192 = 65536
  float* S = ws + 66560;            // 524288
  float* partAcc = ws + 590848;     // NB*TCH*NH*NC = 8388608 (32 MiB)
  float* partML = ws + 8979456;     // 16384
  float* xa = ws + 8995840;         // 262144
  float* p2 = ws + 9257984;         // 32768

  k_wqp<<<64, 256, 0, stream>>>(qt, q_w, q_b, kv_w, q, wqp);
  k_fused<<<NB * TCH, 256, 0, stream>>>(x, mask, wqp, q, kv_b, S, partAcc, partML);
  k_xaw<<<512, 256, 0, stream>>>(partAcc, partML, S, xa, out + NB * NC);
  k_pv<<<2048, 256, 0, stream>>>(xa, kv_w, kv_b, p2);
  k_proj<<<2048, 256, 0, stream>>>(p2, proj_w, proj_b, out);
}

// Round 17
// 104.222 us; speedup vs baseline: 2.2007x; 1.3836x over previous
//
#include <hip/hip_runtime.h>
#include <math.h>

#define NB 32
#define NT 2048
#define NC 1024
#define NH 8
#define ND 128
#define TCH 16                       // t-chunks per batch; chunk = 128 rows
#define SCALE_F 0.08838834764831845f // 1/sqrt(128)

// DPP full-wave sum: VALU-pipe only (no ds_bpermute), ~24-cyc chain.
// rocPRIM gfx9 pattern; old=0 + bound_ctrl=1 -> masked/OOB lanes add 0.
template <int CTRL>
__device__ __forceinline__ float dppadd(float x) {
  int t = __builtin_amdgcn_update_dpp(0, __float_as_int(x), CTRL, 0xf, 0xf, true);
  return x + __int_as_float(t);
}
__device__ __forceinline__ float wredsum(float v) {
  v = dppadd<0x111>(v);  // row_shr:1
  v = dppadd<0x112>(v);  // row_shr:2
  v = dppadd<0x114>(v);  // row_shr:4
  v = dppadd<0x118>(v);  // row_shr:8  -> lanes 15/31/47/63 hold row sums
  v = dppadd<0x142>(v);  // row_bcast:15
  v = dppadd<0x143>(v);  // row_bcast:31 -> lane63 = total
  return __int_as_float(__builtin_amdgcn_readlane(__float_as_int(v), 63));
}

// raw barrier: lgkm-only wait (ds_writes visible), NO vmcnt drain.
__device__ __forceinline__ void barx() {
  asm volatile("s_waitcnt lgkmcnt(0)" ::: "memory");
  __builtin_amdgcn_s_barrier();
  asm volatile("" ::: "memory");
}

// Fused q + split-K wq partial; 64 blocks = 8h x 8dq (16 d-rows each).
__global__ __launch_bounds__(256) void k_wqp(const float* __restrict__ qt,
                                             const float* __restrict__ q_w,
                                             const float* __restrict__ q_b,
                                             const float* __restrict__ kv_w,
                                             float* __restrict__ qout,
                                             float* __restrict__ wqp) {
  __shared__ float qs[16];
  int h = blockIdx.x >> 3, dq = blockIdx.x & 7;
  int tid = threadIdx.x;
  int dbase = h * ND + dq * 16;
  {
    int row = tid >> 4;  // 16 rows x 16 threads
    int cg = tid & 15;
    const float4* qw4 = (const float4*)(q_w + (size_t)(dbase + row) * NC);
    const float4* qt4 = (const float4*)qt;
    float p = 0.f;
#pragma unroll 8
    for (int j = 0; j < 16; ++j) {
      float4 wv = qw4[j * 16 + cg];
      float4 av = qt4[j * 16 + cg];
      p += av.x * wv.x + av.y * wv.y + av.z * wv.z + av.w * wv.w;
    }
    p += __shfl_xor(p, 1, 64);
    p += __shfl_xor(p, 2, 64);
    p += __shfl_xor(p, 4, 64);
    p += __shfl_xor(p, 8, 64);
    if (cg == 0) qs[row] = p + q_b[dbase + row];
  }
  __syncthreads();
  if (tid < 16) qout[dbase + tid] = qs[tid];
  const float4* kw4 = (const float4*)kv_w;
  float4 acc = make_float4(0.f, 0.f, 0.f, 0.f);
#pragma unroll 8
  for (int dd = 0; dd < 16; ++dd) {
    float qv = qs[dd];
    float4 kv = kw4[(size_t)(dbase + dd) * 256 + tid];
    acc.x = fmaf(qv, kv.x, acc.x); acc.y = fmaf(qv, kv.y, acc.y);
    acc.z = fmaf(qv, kv.z, acc.z); acc.w = fmaf(qv, kv.w, acc.w);
  }
  ((float4*)wqp)[dq * 2048 + h * 256 + tid] = acc;
}

// Single pass over x (R14-validated best: TCH=16, 2-row steps, 2-deep
// PA/PB prefetch, lgkm-only barrier, ballot mask, defer-max, DPP wredsum).
__global__ __launch_bounds__(256, 2) void k_fused(
    const float* __restrict__ x, const int* __restrict__ mask,
    const float* __restrict__ wqp, const float* __restrict__ q,
    const float* __restrict__ kv_b,
    float* __restrict__ S, float* __restrict__ partAcc,
    float* __restrict__ partML) {
  __shared__ float4 xs4[2 * 512];  // 2 slots x 2 rows x 256 float4 = 16 KB
  int bi = blockIdx.x;  // b*TCH + tc
  int b = bi >> 4;
  int tc = bi & (TCH - 1);
  int tid = threadIdx.x;
  int w = tid >> 6, lane = tid & 63;
  int h0 = w * 2;
  int tbase = tc * 128;

  const float4* wqp4 = (const float4*)wqp;
  float4 wqv[2][4];
#pragma unroll
  for (int hh = 0; hh < 2; ++hh)
#pragma unroll
    for (int j = 0; j < 4; ++j) {
      int idx = (h0 + hh) * 256 + lane + 64 * j;
      float sx = 0.f, sy = 0.f, sz = 0.f, sw = 0.f;
#pragma unroll
      for (int p = 0; p < 8; ++p) {
        float4 t = wqp4[p * 2048 + idx];
        sx += t.x; sy += t.y; sz += t.z; sw += t.w;
      }
      wqv[hh][j] = make_float4(sx, sy, sz, sw);
    }
  float qkbv[2];
#pragma unroll
  for (int hh = 0; hh < 2; ++hh) {
    float p = 0.f;
    if (lane < 32) {
      float4 qv = ((const float4*)(q + (h0 + hh) * ND))[lane];
      float4 bv = ((const float4*)(kv_b + (h0 + hh) * ND))[lane];
      p = qv.x * bv.x + qv.y * bv.y + qv.z * bv.z + qv.w * bv.w;
    }
    qkbv[hh] = wredsum(p);
  }
  unsigned long long bm0 = __ballot(mask[b * NT + tbase + lane] != 0);
  unsigned long long bm1 = __ballot(mask[b * NT + tbase + 64 + lane] != 0);

  float m[2] = {-INFINITY, -INFINITY};
  float l[2] = {0.f, 0.f};
  float4 acc[2][4];
#pragma unroll
  for (int hh = 0; hh < 2; ++hh)
#pragma unroll
    for (int j = 0; j < 4; ++j) acc[hh][j] = make_float4(0.f, 0.f, 0.f, 0.f);
  float sreg[2][2] = {{0.f, 0.f}, {0.f, 0.f}};

  const float4* x4 = (const float4*)(x + (size_t)(b * NT + tbase) * NC);

  {
    float4 s0 = x4[tid], s1 = x4[256 + tid];
    xs4[tid] = s0;
    xs4[256 + tid] = s1;
  }
  barx();
  float4 pa0 = x4[2 * 256 + tid], pa1 = x4[3 * 256 + tid];
  float4 pb0 = x4[4 * 256 + tid], pb1 = x4[5 * 256 + tid];

#define COMPUTE_STEP(STEP, SLOT)                                               \
  {                                                                            \
    int t0 = tbase + (STEP) * 2;                                               \
    unsigned long long bmx = ((STEP) < 32) ? bm0 : bm1;                        \
    int sh = (2 * (STEP)) & 63;                                                \
    int mk0 = (int)((bmx >> (unsigned)sh) & 1ull);                             \
    int mk1 = (int)((bmx >> (unsigned)(sh + 1)) & 1ull);                       \
    float bias0 = 2.0f * __expf((float)t0 * (-3.0f / 2048.0f));                \
    float bias1 = 2.0f * __expf((float)(t0 + 1) * (-3.0f / 2048.0f));          \
    float4 xv[2][4];                                                           \
    _Pragma("unroll") for (int r = 0; r < 2; ++r)                              \
        _Pragma("unroll") for (int j = 0; j < 4; ++j)                          \
            xv[r][j] = xs4[(SLOT) * 512 + r * 256 + lane + 64 * j];            \
    _Pragma("unroll") for (int hh = 0; hh < 2; ++hh) {                         \
      float d0 = 0.f, d1 = 0.f;                                                \
      _Pragma("unroll") for (int j = 0; j < 4; ++j) {                          \
        float4 wv = wqv[hh][j];                                                \
        d0 = fmaf(xv[0][j].x, wv.x, d0); d0 = fmaf(xv[0][j].y, wv.y, d0);      \
        d0 = fmaf(xv[0][j].z, wv.z, d0); d0 = fmaf(xv[0][j].w, wv.w, d0);      \
        d1 = fmaf(xv[1][j].x, wv.x, d1); d1 = fmaf(xv[1][j].y, wv.y, d1);      \
        d1 = fmaf(xv[1][j].z, wv.z, d1); d1 = fmaf(xv[1][j].w, wv.w, d1);      \
      }                                                                        \
      d0 = wredsum(d0);                                                        \
      d1 = wredsum(d1);                                                        \
      float v0 = mk0 ? (d0 + qkbv[hh]) * SCALE_F + bias0 : -INFINITY;          \
      float v1 = mk1 ? (d1 + qkbv[hh]) * SCALE_F + bias1 : -INFINITY;          \
      sreg[hh][0] = (lane == (STEP)) ? v0 : sreg[hh][0];                       \
      sreg[hh][1] = (lane == (STEP)) ? v1 : sreg[hh][1];                       \
      float pmax = fmaxf(v0, v1);                                              \
      if (pmax > m[hh] + 8.0f) { /* defer-max; wave-uniform */                 \
        float r = __expf(m[hh] - pmax);                                        \
        l[hh] *= r;                                                            \
        _Pragma("unroll") for (int j = 0; j < 4; ++j) {                        \
          acc[hh][j].x *= r; acc[hh][j].y *= r;                                \
          acc[hh][j].z *= r; acc[hh][j].w *= r;                                \
        }                                                                      \
        m[hh] = pmax;                                                          \
      }                                                                        \
      float p0 = mk0 ? __expf(v0 - m[hh]) : 0.f;                               \
      float p1 = mk1 ? __expf(v1 - m[hh]) : 0.f;                               \
      l[hh] += p0 + p1;                                                        \
      _Pragma("unroll") for (int j = 0; j < 4; ++j) {                          \
        acc[hh][j].x = fmaf(p0, xv[0][j].x, fmaf(p1, xv[1][j].x, acc[hh][j].x)); \
        acc[hh][j].y = fmaf(p0, xv[0][j].y, fmaf(p1, xv[1][j].y, acc[hh][j].y)); \
        acc[hh][j].z = fmaf(p0, xv[0][j].z, fmaf(p1, xv[1][j].z, acc[hh][j].z)); \
        acc[hh][j].w = fmaf(p0, xv[0][j].w, fmaf(p1, xv[1][j].w, acc[hh][j].w)); \
      }                                                                        \
    }                                                                          \
  }

  for (int k = 0; k < 32; ++k) {
    COMPUTE_STEP(2 * k, 0)
    xs4[512 + tid] = pa0;
    xs4[512 + 256 + tid] = pa1;
    if (k < 31) {
      pa0 = x4[(4 * k + 6) * 256 + tid];
      pa1 = x4[(4 * k + 7) * 256 + tid];
    }
    barx();
    COMPUTE_STEP(2 * k + 1, 1)
    if (k < 31) {
      xs4[tid] = pb0;
      xs4[256 + tid] = pb1;
      if (k < 30) {
        pb0 = x4[(4 * k + 8) * 256 + tid];
        pb1 = x4[(4 * k + 9) * 256 + tid];
      }
      barx();
    }
  }
#undef COMPUTE_STEP

  // raw-score store: all 64 lanes own rows (lane k -> rows 2k,2k+1)
#pragma unroll
  for (int hh = 0; hh < 2; ++hh) {
    float2 sv = make_float2(sreg[hh][0], sreg[hh][1]);
    float2* sp = (float2*)(S + ((size_t)(b * NH + h0 + hh)) * NT + tbase);
    sp[lane] = sv;
  }
  float4* pA = (float4*)(partAcc + (size_t)bi * (NH * NC));
#pragma unroll
  for (int hh = 0; hh < 2; ++hh)
#pragma unroll
    for (int j = 0; j < 4; ++j)
      pA[(h0 + hh) * 256 + lane + 64 * j] = acc[hh][j];
  if (lane == 0) {
#pragma unroll
    for (int hh = 0; hh < 2; ++hh) {
      partML[(bi * NH + h0 + hh) * 2] = m[hh];
      partML[(bi * NH + h0 + hh) * 2 + 1] = l[hh];
    }
  }
}

// Merged xa-reduce + attn_weights (TCH=16 reductions; R11/R14-validated).
__global__ __launch_bounds__(256) void k_xaw(const float* __restrict__ partAcc,
                                             const float* __restrict__ partML,
                                             const float* __restrict__ S,
                                             float* __restrict__ xa,
                                             float* __restrict__ ow) {
  __shared__ float Ms[NH], Is[NH];
  int blk = blockIdx.x;
  int tid = threadIdx.x;
  if (blk < NB * NH) {  // ---- xa role ----
    int b = blk >> 3, h = blk & 7;
    float mv = -INFINITY, lv = 0.f;
    if (tid < TCH) {
      mv = partML[((b * TCH + tid) * NH + h) * 2];
      lv = partML[((b * TCH + tid) * NH + h) * 2 + 1];
    }
    float Mg = mv;
#pragma unroll
    for (int off = 8; off > 0; off >>= 1) Mg = fmaxf(Mg, __shfl_xor(Mg, off, 64));
    float contrib = (tid < TCH && mv != -INFINITY) ? __expf(mv - Mg) * lv : 0.f;
#pragma unroll
    for (int off = 8; off > 0; off >>= 1) contrib += __shfl_xor(contrib, off, 64);
    if (tid == 0) {
      Ms[0] = Mg;
      Is[0] = (contrib > 0.f) ? 1.f / contrib : 0.f;
    }
    __syncthreads();
    float Mgb = Ms[0], inv = Is[0];
    float4 sacc = make_float4(0.f, 0.f, 0.f, 0.f);
    for (int tc = 0; tc < TCH; ++tc) {
      int pi = (b * TCH + tc) * NH + h;
      float mw = partML[pi * 2];
      if (mw == -INFINITY) continue;
      float scl = __expf(mw - Mgb);
      float4 v = ((const float4*)partAcc)[(size_t)pi * 256 + tid];
      sacc.x = fmaf(scl, v.x, sacc.x); sacc.y = fmaf(scl, v.y, sacc.y);
      sacc.z = fmaf(scl, v.z, sacc.z); sacc.w = fmaf(scl, v.w, sacc.w);
    }
    sacc.x *= inv; sacc.y *= inv; sacc.z *= inv; sacc.w *= inv;
    ((float4*)xa)[(size_t)blk * 256 + tid] = sacc;
  } else {  // ---- attn_weights role ----
    int blkb = blk - NB * NH;
    int b = blkb >> 3, tch = blkb & 7;
    int hh = tid >> 4, tcc = tid & 15;  // 8 heads x 16 chunks in tid<128
    float mv = -INFINITY, lv = 0.f;
    if (tid < 128) {
      mv = partML[((b * TCH + tcc) * NH + hh) * 2];
      lv = partML[((b * TCH + tcc) * NH + hh) * 2 + 1];
    }
    float Mg = mv;
#pragma unroll
    for (int off = 8; off > 0; off >>= 1) Mg = fmaxf(Mg, __shfl_xor(Mg, off, 64));
    float contrib = (tid < 128 && mv != -INFINITY) ? __expf(mv - Mg) * lv : 0.f;
#pragma unroll
    for (int off = 8; off > 0; off >>= 1) contrib += __shfl_xor(contrib, off, 64);
    if (tid < 128 && tcc == 0) {
      Ms[hh] = Mg;
      Is[hh] = (contrib > 0.f) ? 1.f / contrib : 0.f;
    }
    __syncthreads();
    int t = tch * 256 + tid;
    float a = 0.f;
#pragma unroll
    for (int h = 0; h < NH; ++h) {
      float s = S[((size_t)(b * NH + h)) * NT + t];
      a += (s == -INFINITY) ? 0.f : __expf(s - Ms[h]) * Is[h];
    }
    ow[(size_t)b * NT + t] = a * 0.125f;
  }
}

// p2: wave per (bgroup of 4, hd) — weight row loaded ONCE for 4 b's.
__global__ __launch_bounds__(256) void k_pv(const float* __restrict__ xa,
                                            const float* __restrict__ kv_w,
                                            const float* __restrict__ kv_b,
                                            float* __restrict__ p2) {
  int gw = (blockIdx.x * 256 + threadIdx.x) >> 6;  // [0, 8192)
  int lane = threadIdx.x & 63;
  int hd = gw & (NC - 1);
  int bg = gw >> 10;  // [0,8): b = 4*bg .. 4*bg+3
  int h = hd >> 7;
  const float4* w4 = (const float4*)(kv_w + ((size_t)(NC + hd)) * NC);
  float4 wv[4];
#pragma unroll
  for (int j = 0; j < 4; ++j) wv[j] = w4[lane + 64 * j];
  float accv[4] = {0.f, 0.f, 0.f, 0.f};
#pragma unroll
  for (int i = 0; i < 4; ++i) {
    const float4* a4 =
        (const float4*)(xa + ((size_t)((bg * 4 + i) * NH + h)) * NC);
#pragma unroll
    for (int j = 0; j < 4; ++j) {
      float4 a = a4[lane + 64 * j];
      accv[i] += a.x * wv[j].x + a.y * wv[j].y + a.z * wv[j].z + a.w * wv[j].w;
    }
  }
#pragma unroll
  for (int i = 0; i < 4; ++i) accv[i] = wredsum(accv[i]);
  if (lane == 0) {
    float bias = kv_b[NC + hd];
#pragma unroll
    for (int i = 0; i < 4; ++i)
      p2[(size_t)(bg * 4 + i) * NC + hd] = accv[i] + bias;
  }
}

// out: wave per (bgroup of 4, i) — same 4-b restructure as k_pv.
__global__ __launch_bounds__(256) void k_proj(const float* __restrict__ p2,
                                              const float* __restrict__ proj_w,
                                              const float* __restrict__ proj_b,
                                              float* __restrict__ out) {
  int gw = (blockIdx.x * 256 + threadIdx.x) >> 6;  // [0, 8192)
  int lane = threadIdx.x & 63;
  int i = gw & (NC - 1);
  int bg = gw >> 10;
  const float4* w4 = (const float4*)(proj_w + (size_t)i * NC);
  float4 wv[4];
#pragma unroll
  for (int j = 0; j < 4; ++j) wv[j] = w4[lane + 64 * j];
  float accv[4] = {0.f, 0.f, 0.f, 0.f};
#pragma unroll
  for (int k = 0; k < 4; ++k) {
    const float4* a4 = (const float4*)(p2 + (size_t)(bg * 4 + k) * NC);
#pragma unroll
    for (int j = 0; j < 4; ++j) {
      float4 a = a4[lane + 64 * j];
      accv[k] += a.x * wv[j].x + a.y * wv[j].y + a.z * wv[j].z + a.w * wv[j].w;
    }
  }
#pragma unroll
  for (int k = 0; k < 4; ++k) accv[k] = wredsum(accv[k]);
  if (lane == 0) {
    float bias = proj_b[i];
#pragma unroll
    for (int k = 0; k < 4; ++k)
      out[(size_t)(bg * 4 + k) * NC + i] = accv[k] + bias;
  }
}

extern "C" void kernel_launch(void* const* d_in, const int* in_sizes, int n_in,
                              void* d_out, int out_size, void* d_ws, size_t ws_size,
                              hipStream_t stream) {
  const float* x = (const float*)d_in[0];
  const int* mask = (const int*)d_in[1];
  const float* qt = (const float*)d_in[2];
  const float* kv_w = (const float*)d_in[3];
  const float* kv_b = (const float*)d_in[4];
  const float* q_w = (const float*)d_in[5];
  const float* q_b = (const float*)d_in[6];
  const float* proj_w = (const float*)d_in[7];
  const float* proj_b = (const float*)d_in[8];
  float* out = (float*)d_out;

  float* ws = (float*)d_ws;
  float* q = ws;                    // 1024
  float* wqp = ws + 1024;           // 8*8192 = 65536
  float* S = ws + 66560;            // 524288
  float* partAcc = ws + 590848;     // NB*TCH*NH*NC = 4194304 (16 MiB)
  float* partML = ws + 4785152;     // NB*TCH*NH*2 = 8192
  float* xa = ws + 4793344;         // 262144
  float* p2 = ws + 5055488;         // 32768

  k_wqp<<<64, 256, 0, stream>>>(qt, q_w, q_b, kv_w, q, wqp);
  k_fused<<<NB * TCH, 256, 0, stream>>>(x, mask, wqp, q, kv_b, S, partAcc, partML);
  k_xaw<<<512, 256, 0, stream>>>(partAcc, partML, S, xa, out + NB * NC);
  k_pv<<<2048, 256, 0, stream>>>(xa, kv_w, kv_b, p2);
  k_proj<<<2048, 256, 0, stream>>>(p2, proj_w, proj_b, out);
}